// Round 5
// baseline (255.549 us; speedup 1.0000x reference)
//
#include <hip/hip_runtime.h>
#include <float.h>

// Problem constants (B=16, T=2048, D=256, K=1024)
constexpr int kD = 256;
constexpr int kK = 1024;
constexpr int kN = 16 * 2048;   // 32768 rows

using bf16x8 = __attribute__((ext_vector_type(8))) short;
using f32x16 = __attribute__((ext_vector_type(16))) float;
using u16x8  = __attribute__((ext_vector_type(8))) unsigned short;

__device__ __forceinline__ unsigned short f2bf(float x) {
    union { float f; unsigned u; } a; a.f = x;
    const unsigned u = a.u;
    return (unsigned short)((u + 0x7fffu + ((u >> 16) & 1u)) >> 16);   // RNE
}
__device__ __forceinline__ float bf2f(unsigned short b) {
    union { unsigned u; float f; } a; a.u = ((unsigned)b) << 16;
    return a.f;
}

#define GLOAD_LDS16(GP, LP) \
    __builtin_amdgcn_global_load_lds((const __attribute__((address_space(1))) unsigned int*)(GP), \
                                     (__attribute__((address_space(3))) unsigned int*)(LP), 16, 0, 0)

// ---------------------------------------------------------------------------
// Split fp32 rows into (h,m,l) bf16 triples in MFMA fragment-image order
// (identical to the R3-validated layout). For 64-row block RB, unit u:
//   l=u&63, f=(u>>6)&1, t16=u>>7
//   row = RB*64 + f*32 + (l&31); d0 = t16*16 + (l>>5)*8
//   shorts offset = RB*16384 + t16*1024 + f*512 + l*8   <-- d-chunk stride 1024!
__global__ void vq_split_kernel(const float* __restrict__ src,
                                unsigned short* __restrict__ oh,
                                unsigned short* __restrict__ om,
                                unsigned short* __restrict__ ol) {
    const int RB = blockIdx.x;
    const int t  = threadIdx.x;
    #pragma unroll
    for (int it = 0; it < 8; ++it) {
        const int u   = it * 256 + t;
        const int l   = u & 63;
        const int f   = (u >> 6) & 1;
        const int t16 = u >> 7;
        const int row = RB * 64 + f * 32 + (l & 31);
        const int d0  = t16 * 16 + (l >> 5) * 8;
        const float4 v0 = *reinterpret_cast<const float4*>(src + (size_t)row * kD + d0);
        const float4 v1 = *reinterpret_cast<const float4*>(src + (size_t)row * kD + d0 + 4);
        const float x[8] = {v0.x, v0.y, v0.z, v0.w, v1.x, v1.y, v1.z, v1.w};
        u16x8 H, M, L;
        #pragma unroll
        for (int e = 0; e < 8; ++e) {
            const unsigned short h = f2bf(x[e]);
            const float r1 = x[e] - bf2f(h);          // exact
            const unsigned short m = f2bf(r1);
            const float r2 = r1 - bf2f(m);            // exact
            const unsigned short lo = f2bf(r2);
            H[e] = (short)h; M[e] = (short)m; L[e] = (short)lo;
        }
        const size_t o = (size_t)RB * 16384 + (size_t)u * 8;
        *reinterpret_cast<u16x8*>(oh + o) = H;
        *reinterpret_cast<u16x8*>(om + o) = M;
        *reinterpret_cast<u16x8*>(ol + o) = L;
    }
}

// ---------------------------------------------------------------------------
// Split for E, with csqr fused (||c||^2 per code row, fp32).
__global__ void vq_split_csqr_kernel(const float* __restrict__ src,
                                     unsigned short* __restrict__ oh,
                                     unsigned short* __restrict__ om,
                                     unsigned short* __restrict__ ol,
                                     float* __restrict__ csqr) {
    __shared__ float part[64][4];
    const int RB = blockIdx.x;
    const int t  = threadIdx.x;
    #pragma unroll
    for (int it = 0; it < 8; ++it) {
        const int u   = it * 256 + t;
        const int l   = u & 63;
        const int f   = (u >> 6) & 1;
        const int t16 = u >> 7;
        const int row = RB * 64 + f * 32 + (l & 31);
        const int d0  = t16 * 16 + (l >> 5) * 8;
        const float4 v0 = *reinterpret_cast<const float4*>(src + (size_t)row * kD + d0);
        const float4 v1 = *reinterpret_cast<const float4*>(src + (size_t)row * kD + d0 + 4);
        const float x[8] = {v0.x, v0.y, v0.z, v0.w, v1.x, v1.y, v1.z, v1.w};
        u16x8 H, M, L;
        #pragma unroll
        for (int e = 0; e < 8; ++e) {
            const unsigned short h = f2bf(x[e]);
            const float r1 = x[e] - bf2f(h);
            const unsigned short m = f2bf(r1);
            const float r2 = r1 - bf2f(m);
            const unsigned short lo = f2bf(r2);
            H[e] = (short)h; M[e] = (short)m; L[e] = (short)lo;
        }
        const size_t o = (size_t)RB * 16384 + (size_t)u * 8;
        *reinterpret_cast<u16x8*>(oh + o) = H;
        *reinterpret_cast<u16x8*>(om + o) = M;
        *reinterpret_cast<u16x8*>(ol + o) = L;
    }
    // csqr: 4 threads per row, each sums a 64-elem quarter.
    const int r = t >> 2, q = t & 3;
    const float* rp = src + (size_t)(RB * 64 + r) * kD + q * 64;
    float s = 0.0f;
    #pragma unroll
    for (int i = 0; i < 16; ++i) {
        const float4 v = reinterpret_cast<const float4*>(rp)[i];
        s += v.x * v.x + v.y * v.y + v.z * v.z + v.w * v.w;
    }
    part[r][q] = s;
    __syncthreads();
    if (t < 64) csqr[RB * 64 + t] = part[t][0] + part[t][1] + part[t][2] + part[t][3];
}

// ---------------------------------------------------------------------------
// MFMA distance GEMM (6-pass bf16x3 == fp32-exact) + fused argmin.
// Block tile 256 rows x 128 cols; 4 waves (2x2); wave tile 128x64 = 4x2
// MFMAs of 32x32x16 -> acc 128 VGPR, 2 waves/SIMD. DC=16 per chunk (t16=c),
// double-buffered LDS (2 x 36 KB). Stage(c+1) issue -> compute(c) -> barrier.
// dist(r,c) = csqr[c] - 2*dot  (||x||^2 dropped: argmin-invariant per row).
__global__ __launch_bounds__(256, 2) void vq_gemm_kernel(
    const unsigned short* __restrict__ xh, const unsigned short* __restrict__ xm,
    const unsigned short* __restrict__ xl,
    const unsigned short* __restrict__ eh, const unsigned short* __restrict__ em,
    const unsigned short* __restrict__ el,
    const float* __restrict__ csqr,
    float* __restrict__ cand_val, int* __restrict__ cand_idx)
{
    // per buffer: A = 24 segs (4 rbg x 2 f x 3 lv), B = 12 segs, 1 KB each
    __shared__ bf16x8 smem[2][2304];      // 72 KB total
    const int tid  = threadIdx.x;
    const int lane = tid & 63;
    const int wid  = tid >> 6;
    const int wr   = wid >> 1;            // wave row half (128 rows)
    const int wc   = wid & 1;             // wave col half (64 cols)

    // XCD-bijective: 8 col-blocks of one 256-row panel land on one XCD.
    const int w    = blockIdx.x;          // 1024 blocks
    const int xcd  = w & 7;
    const int slot = w >> 3;              // 0..127
    const int rbp  = xcd * 16 + (slot >> 3);   // 0..127 row panel (256 rows)
    const int cbp  = slot & 7;                 // 0..7  col block (128 codes)

    // Precompute the 9 staging descriptors for this wave (36 segs / 4 waves).
    const unsigned short* gbase[9];
    int ldsoff[9];
    #pragma unroll
    for (int k2 = 0; k2 < 9; ++k2) {
        const int s = wid * 9 + k2;
        const bool isB = s >= 24;
        const int q   = isB ? s - 24 : s;
        const int grp = q / 6;                 // rbg 0..3 | cbg 0..1
        const int rem = q % 6;
        const int f   = rem / 3;
        const int lv  = rem % 3;
        const unsigned short* img = isB ? (lv == 0 ? eh : lv == 1 ? em : el)
                                        : (lv == 0 ? xh : lv == 1 ? xm : xl);
        const int RBx = isB ? (cbp * 2 + grp) : (rbp * 4 + grp);
        gbase[k2] = img + (size_t)RBx * 16384 + f * 512 + lane * 8;
        ldsoff[k2] = (isB ? 1536 + q * 64 : q * 64);
    }

    f32x16 acc[4][2];
    #pragma unroll
    for (int m = 0; m < 4; ++m) { acc[m][0] = (f32x16)0.0f; acc[m][1] = (f32x16)0.0f; }

    // A frag unit bases (element index into smem buffer), per m and lv(+lv*64)
    int au[4], bu[2];
    #pragma unroll
    for (int m = 0; m < 4; ++m) au[m] = ((wr * 2 + (m >> 1)) * 6 + (m & 1) * 3) * 64 + lane;
    #pragma unroll
    for (int n = 0; n < 2; ++n) bu[n] = 1536 + (wc * 6 + n * 3) * 64 + lane;

    // prologue: stage chunk 0
    #pragma unroll
    for (int k2 = 0; k2 < 9; ++k2) GLOAD_LDS16(gbase[k2], &smem[0][ldsoff[k2]]);
    __syncthreads();

    for (int c = 0; c < 16; ++c) {
        const int cur = c & 1;
        if (c < 15) {
            #pragma unroll
            for (int k2 = 0; k2 < 9; ++k2)     // d-chunk stride = 1024 shorts (t16*1024)
                GLOAD_LDS16(gbase[k2] + (size_t)(c + 1) * 1024, &smem[cur ^ 1][ldsoff[k2]]);
        }
        // compute chunk c from smem[cur]
        const bf16x8* sb = smem[cur];
        bf16x8 A[3][4];
        #pragma unroll
        for (int m = 0; m < 4; ++m) {
            A[0][m] = sb[au[m]]; A[1][m] = sb[au[m] + 64]; A[2][m] = sb[au[m] + 128];
        }
#define MFMA(a, b, cacc) __builtin_amdgcn_mfma_f32_32x32x16_bf16(a, b, cacc, 0, 0, 0)
        #pragma unroll
        for (int n = 0; n < 2; ++n) {
            const bf16x8 bh = sb[bu[n]], bm = sb[bu[n] + 64], bl = sb[bu[n] + 128];
            #pragma unroll
            for (int m = 0; m < 4; ++m) {
                f32x16 a5 = acc[m][n];
                a5 = MFMA(A[0][m], bh, a5);      // hh
                a5 = MFMA(A[0][m], bm, a5);      // hm
                a5 = MFMA(A[1][m], bh, a5);      // mh
                a5 = MFMA(A[0][m], bl, a5);      // hl
                a5 = MFMA(A[2][m], bh, a5);      // lh
                a5 = MFMA(A[1][m], bm, a5);      // mm
                acc[m][n] = a5;
            }
        }
#undef MFMA
        __syncthreads();
    }

    // Fused argmin epilogue. C/D layout: col = lane&31,
    // row = (reg&3) + 8*(reg>>2) + 4*(lane>>5)  [verified R2/R3].
    const int colbase = cbp * 128 + wc * 64;
    const float cs0 = csqr[colbase + (lane & 31)];
    const float cs1 = csqr[colbase + 32 + (lane & 31)];
    const int rowbase = rbp * 256 + wr * 128 + 4 * (lane >> 5);
    const int cslot = cbp * 2 + wc;           // 16 slots, ascending col order

    #pragma unroll
    for (int m = 0; m < 4; ++m) {
        #pragma unroll
        for (int r = 0; r < 16; ++r) {
            float bv = fmaf(-2.0f, acc[m][0][r], cs0);
            int   bi = colbase + (lane & 31);
            const float v1 = fmaf(-2.0f, acc[m][1][r], cs1);
            if (v1 < bv) { bv = v1; bi = colbase + 32 + (lane & 31); }
            #pragma unroll
            for (int mk = 16; mk >= 1; mk >>= 1) {      // reduce within 32-lane half
                const float ov = __shfl_xor(bv, mk);
                const int   oi = __shfl_xor(bi, mk);
                if (ov < bv || (ov == bv && oi < bi)) { bv = ov; bi = oi; }
            }
            if ((lane & 31) == 0) {
                const int row = rowbase + m * 32 + (r & 3) + 8 * (r >> 2);
                cand_val[(size_t)cslot * kN + row] = bv;
                cand_idx[(size_t)cslot * kN + row] = bi;
            }
        }
    }
}

// ---------------------------------------------------------------------------
// Combine 16 per-column-slot candidates per row (ascending slot == ascending
// code range -> first-occurrence tie semantics).
__global__ void vq_combine_kernel(const float* __restrict__ cand_val,
                                  const int* __restrict__ cand_idx,
                                  int* __restrict__ idx, float* __restrict__ idxf)
{
    const int row = blockIdx.x * 256 + threadIdx.x;
    float bv = cand_val[row];
    int   bi = cand_idx[row];
    #pragma unroll
    for (int s = 1; s < 16; ++s) {
        const float v = cand_val[(size_t)s * kN + row];
        const int  i2 = cand_idx[(size_t)s * kN + row];
        if (v < bv || (v == bv && i2 < bi)) { bv = v; bi = i2; }
    }
    idx[row]  = bi;
    idxf[row] = (float)bi;
}

// ---------------------------------------------------------------------------
// Gather codes -> z_q_x and z_q_x_bar (identical in eval mode).
__global__ void vq_gather_kernel(const float* __restrict__ E, const int* __restrict__ idx,
                                 float* __restrict__ zq, float* __restrict__ zqb) {
    const int row = blockIdx.x * 4 + (threadIdx.x >> 6);
    const int lane = threadIdx.x & 63;
    const int k = idx[row];
    const float4 v = reinterpret_cast<const float4*>(E + (size_t)k * kD)[lane];
    reinterpret_cast<float4*>(zq + (size_t)row * kD)[lane] = v;
    reinterpret_cast<float4*>(zqb + (size_t)row * kD)[lane] = v;
}

// ---------------------------------------------------------------------------
extern "C" void kernel_launch(void* const* d_in, const int* in_sizes, int n_in,
                              void* d_out, int out_size, void* d_ws, size_t ws_size,
                              hipStream_t stream) {
    const float* X = (const float*)d_in[0];      // z_e_x  [N, D]
    const float* E = (const float*)d_in[1];      // embedding [K, D]

    float* out  = (float*)d_out;
    float* zq   = out;                           // [N*D]
    float* zqb  = out + (size_t)kN * kD;         // [N*D]
    float* idxf = out + 2 * (size_t)kN * kD;     // [N]

    // Big scratch in d_out ([0,52MB)); fully consumed before gather overwrites
    // [0,64MB) (combine reads cand BEFORE gather runs; stream order).
    char* ob = (char*)d_out;
    unsigned short* XIh = (unsigned short*)ob;                   // 16 MB
    unsigned short* XIm = XIh + (size_t)kN * kD;                 // 16 MB
    unsigned short* XIl = XIm + (size_t)kN * kD;                 // 16 MB
    float* cand_val = (float*)(ob + 3ull * kN * kD * 2);                // 2 MB @48MB
    int*   cand_idx = (int*)(ob + 3ull * kN * kD * 2 + 16ull * kN * 4); // 2 MB

    // Small scratch in ws (~1.7 MB)
    char* ws = (char*)d_ws;
    float* csqr = (float*)ws;
    unsigned short* EIh = (unsigned short*)(ws + 4096);
    unsigned short* EIm = EIh + (size_t)kK * kD;
    unsigned short* EIl = EIm + (size_t)kK * kD;
    int* idx = (int*)(ws + 4096 + 3ull * kK * kD * 2);

    vq_split_kernel<<<kN / 64, 256, 0, stream>>>(X, XIh, XIm, XIl);
    vq_split_csqr_kernel<<<kK / 64, 256, 0, stream>>>(E, EIh, EIm, EIl, csqr);
    vq_gemm_kernel<<<(kN / 256) * (kK / 128), 256, 0, stream>>>(
        XIh, XIm, XIl, EIh, EIm, EIl, csqr, cand_val, cand_idx);
    vq_combine_kernel<<<kN / 256, 256, 0, stream>>>(cand_val, cand_idx, idx, idxf);
    vq_gather_kernel<<<kN / 4, 256, 0, stream>>>(E, idx, zq, zqb);
}

// Round 6
// 250.702 us; speedup vs baseline: 1.0193x; 1.0193x over previous
//
#include <hip/hip_runtime.h>
#include <float.h>

// Problem constants (B=16, T=2048, D=256, K=1024)
constexpr int kD = 256;
constexpr int kK = 1024;
constexpr int kN = 16 * 2048;   // 32768 rows

using bf16x8 = __attribute__((ext_vector_type(8))) short;
using f32x16 = __attribute__((ext_vector_type(16))) float;
using u16x8  = __attribute__((ext_vector_type(8))) unsigned short;

__device__ __forceinline__ unsigned short f2bf(float x) {
    union { float f; unsigned u; } a; a.f = x;
    const unsigned u = a.u;
    return (unsigned short)((u + 0x7fffu + ((u >> 16) & 1u)) >> 16);   // RNE
}
__device__ __forceinline__ float bf2f(unsigned short b) {
    union { unsigned u; float f; } a; a.u = ((unsigned)b) << 16;
    return a.f;
}

#define GLOAD_LDS16(GP, LP) \
    __builtin_amdgcn_global_load_lds((const __attribute__((address_space(1))) unsigned int*)(GP), \
                                     (__attribute__((address_space(3))) unsigned int*)(LP), 16, 0, 0)

// ---------------------------------------------------------------------------
// Fused split: blocks [0,512) split X, blocks [512,528) split E (+csqr).
// Image layout (validated R3/R5): for 64-row block RB, unit u in [0,2048):
//   l=u&63, f=(u>>6)&1, t16=u>>7
//   row = RB*64 + f*32 + (l&31); d0 = t16*16 + (l>>5)*8
//   shorts offset = RB*16384 + t16*1024 + f*512 + l*8   (d-chunk stride 1024)
__global__ void vq_split_all_kernel(const float* __restrict__ X, const float* __restrict__ E,
                                    unsigned short* __restrict__ xh, unsigned short* __restrict__ xm,
                                    unsigned short* __restrict__ xl,
                                    unsigned short* __restrict__ eh, unsigned short* __restrict__ em,
                                    unsigned short* __restrict__ el,
                                    float* __restrict__ csqr) {
    __shared__ float part[64][4];
    const int b   = blockIdx.x;
    const bool isE = b >= 512;
    const int RB  = isE ? b - 512 : b;
    const float* src = isE ? E : X;
    unsigned short* oh = isE ? eh : xh;
    unsigned short* om = isE ? em : xm;
    unsigned short* ol = isE ? el : xl;
    const int t = threadIdx.x;
    #pragma unroll
    for (int it = 0; it < 8; ++it) {
        const int u   = it * 256 + t;
        const int l   = u & 63;
        const int f   = (u >> 6) & 1;
        const int t16 = u >> 7;
        const int row = RB * 64 + f * 32 + (l & 31);
        const int d0  = t16 * 16 + (l >> 5) * 8;
        const float4 v0 = *reinterpret_cast<const float4*>(src + (size_t)row * kD + d0);
        const float4 v1 = *reinterpret_cast<const float4*>(src + (size_t)row * kD + d0 + 4);
        const float x[8] = {v0.x, v0.y, v0.z, v0.w, v1.x, v1.y, v1.z, v1.w};
        u16x8 H, M, L;
        #pragma unroll
        for (int e = 0; e < 8; ++e) {
            const unsigned short h = f2bf(x[e]);
            const float r1 = x[e] - bf2f(h);          // exact
            const unsigned short m = f2bf(r1);
            const float r2 = r1 - bf2f(m);            // exact
            const unsigned short lo = f2bf(r2);
            H[e] = (short)h; M[e] = (short)m; L[e] = (short)lo;
        }
        const size_t o = (size_t)RB * 16384 + (size_t)u * 8;
        *reinterpret_cast<u16x8*>(oh + o) = H;
        *reinterpret_cast<u16x8*>(om + o) = M;
        *reinterpret_cast<u16x8*>(ol + o) = L;
    }
    if (isE) {
        // csqr: 4 threads per code row, each sums a 64-elem quarter.
        const int r = t >> 2, q = t & 3;
        const float* rp = E + (size_t)(RB * 64 + r) * kD + q * 64;
        float s = 0.0f;
        #pragma unroll
        for (int i = 0; i < 16; ++i) {
            const float4 v = reinterpret_cast<const float4*>(rp)[i];
            s += v.x * v.x + v.y * v.y + v.z * v.z + v.w * v.w;
        }
        part[r][q] = s;
        __syncthreads();
        if (t < 64) csqr[RB * 64 + t] = part[t][0] + part[t][1] + part[t][2] + part[t][3];
    }
}

// ---------------------------------------------------------------------------
// MFMA distance GEMM (6-pass bf16x3 == fp32-exact) + fused argmin via
// sortable-u64 atomicMin. Counted-vmcnt pipeline (T3+T4): stage(c+1)'s 9
// loads stay in flight across the barrier; main loop never drains vmcnt to 0.
// dist(r,c) = csqr[c] - 2*dot  (||x||^2 dropped: argmin-invariant per row).
__global__ __launch_bounds__(256, 2) void vq_gemm_kernel(
    const unsigned short* __restrict__ xh, const unsigned short* __restrict__ xm,
    const unsigned short* __restrict__ xl,
    const unsigned short* __restrict__ eh, const unsigned short* __restrict__ em,
    const unsigned short* __restrict__ el,
    const float* __restrict__ csqr,
    unsigned long long* __restrict__ rowkey)
{
    // per buffer: A = 24 segs (4 rbg x 2 f x 3 lv), B = 12 segs, 1 KB each
    __shared__ bf16x8 smem[2][2304];      // 72 KB total
    const int tid  = threadIdx.x;
    const int lane = tid & 63;
    const int wid  = tid >> 6;
    const int wr   = wid >> 1;            // wave row half (128 rows)
    const int wc   = wid & 1;             // wave col half (64 cols)

    // XCD-bijective: 8 col-blocks of one 256-row panel land on one XCD.
    const int w    = blockIdx.x;          // 1024 blocks
    const int xcd  = w & 7;
    const int slot = w >> 3;              // 0..127
    const int rbp  = xcd * 16 + (slot >> 3);   // 0..127 row panel (256 rows)
    const int cbp  = slot & 7;                 // 0..7  col block (128 codes)

    // 9 staging descriptors per wave (36 segs / 4 waves).
    const unsigned short* gbase[9];
    int ldsoff[9];
    #pragma unroll
    for (int k2 = 0; k2 < 9; ++k2) {
        const int s = wid * 9 + k2;
        const bool isB = s >= 24;
        const int q   = isB ? s - 24 : s;
        const int grp = q / 6;                 // rbg 0..3 | cbg 0..1
        const int rem = q % 6;
        const int f   = rem / 3;
        const int lv  = rem % 3;
        const unsigned short* img = isB ? (lv == 0 ? eh : lv == 1 ? em : el)
                                        : (lv == 0 ? xh : lv == 1 ? xm : xl);
        const int RBx = isB ? (cbp * 2 + grp) : (rbp * 4 + grp);
        gbase[k2] = img + (size_t)RBx * 16384 + f * 512 + lane * 8;
        ldsoff[k2] = (isB ? 1536 + q * 64 : q * 64);
    }

    f32x16 acc[4][2];
    #pragma unroll
    for (int m = 0; m < 4; ++m) { acc[m][0] = (f32x16)0.0f; acc[m][1] = (f32x16)0.0f; }

    int au[4], bu[2];
    #pragma unroll
    for (int m = 0; m < 4; ++m) au[m] = ((wr * 2 + (m >> 1)) * 6 + (m & 1) * 3) * 64 + lane;
    #pragma unroll
    for (int n = 0; n < 2; ++n) bu[n] = 1536 + (wc * 6 + n * 3) * 64 + lane;

#define MFMA(a, b, cacc) __builtin_amdgcn_mfma_f32_32x32x16_bf16(a, b, cacc, 0, 0, 0)
    auto compute_chunk = [&](const bf16x8* sb) {
        bf16x8 A0[4], A1[4], A2[4];
        #pragma unroll
        for (int m = 0; m < 4; ++m) {
            A0[m] = sb[au[m]]; A1[m] = sb[au[m] + 64]; A2[m] = sb[au[m] + 128];
        }
        __builtin_amdgcn_s_setprio(1);
        #pragma unroll
        for (int n = 0; n < 2; ++n) {
            const bf16x8 bh = sb[bu[n]], bm = sb[bu[n] + 64], bl = sb[bu[n] + 128];
            #pragma unroll
            for (int m = 0; m < 4; ++m) {
                f32x16 a5 = acc[m][n];
                a5 = MFMA(A0[m], bh, a5);      // hh
                a5 = MFMA(A0[m], bm, a5);      // hm
                a5 = MFMA(A1[m], bh, a5);      // mh
                a5 = MFMA(A0[m], bl, a5);      // hl
                a5 = MFMA(A2[m], bh, a5);      // lh
                a5 = MFMA(A1[m], bm, a5);      // mm
                acc[m][n] = a5;
            }
        }
        __builtin_amdgcn_s_setprio(0);
    };
#undef MFMA
// keep MFMA macro local to lambda body via re-expansion below
#define MFMA(a, b, cacc) __builtin_amdgcn_mfma_f32_32x32x16_bf16(a, b, cacc, 0, 0, 0)

    // Prologue: stage chunks 0 and 1 (18 loads in flight).
    #pragma unroll
    for (int k2 = 0; k2 < 9; ++k2) GLOAD_LDS16(gbase[k2], &smem[0][ldsoff[k2]]);
    #pragma unroll
    for (int k2 = 0; k2 < 9; ++k2) GLOAD_LDS16(gbase[k2] + 1024, &smem[1][ldsoff[k2]]);

    #pragma unroll 1
    for (int c = 0; c < 15; ++c) {
        const int cur = c & 1;
        // my chunk-c loads done; chunk-(c+1)'s 9 stay in flight across barrier
        asm volatile("s_waitcnt vmcnt(9)" ::: "memory");
        __builtin_amdgcn_s_barrier();
        asm volatile("" ::: "memory");
        compute_chunk(smem[cur]);
        asm volatile("" ::: "memory");
        __builtin_amdgcn_s_barrier();      // all waves' ds_reads of smem[cur] done
        asm volatile("" ::: "memory");
        if (c < 14) {                       // stage chunk c+2 into freed buffer
            #pragma unroll
            for (int k2 = 0; k2 < 9; ++k2)
                GLOAD_LDS16(gbase[k2] + (size_t)(c + 2) * 1024, &smem[cur][ldsoff[k2]]);
        }
    }
    // Tail: chunk 15 (only its 9 loads can remain in flight).
    asm volatile("s_waitcnt vmcnt(0)" ::: "memory");
    __builtin_amdgcn_s_barrier();
    asm volatile("" ::: "memory");
    compute_chunk(smem[1]);
#undef MFMA

    // Epilogue. C/D layout: col = lane&31, row = (reg&3)+8*(reg>>2)+4*(lane>>5).
    const int lane31 = lane & 31;
    const int colbase = cbp * 128 + wc * 64;
    const float cs0 = csqr[colbase + lane31];
    const float cs1 = csqr[colbase + 32 + lane31];
    const int rowbase = rbp * 256 + wr * 128 + 4 * (lane >> 5);

    #pragma unroll
    for (int m = 0; m < 4; ++m) {
        #pragma unroll
        for (int r = 0; r < 16; ++r) {
            float bv = fmaf(-2.0f, acc[m][0][r], cs0);
            int   bi = colbase + lane31;
            const float v1 = fmaf(-2.0f, acc[m][1][r], cs1);
            if (v1 < bv) { bv = v1; bi = colbase + 32 + lane31; }   // ascending col: '<' keeps first
            #pragma unroll
            for (int mk = 16; mk >= 1; mk >>= 1) {      // reduce within 32-lane half
                const float ov = __shfl_xor(bv, mk);
                const int   oi = __shfl_xor(bi, mk);
                if (ov < bv || (ov == bv && oi < bi)) { bv = ov; bi = oi; }
            }
            if (lane31 == 0) {
                const int row = rowbase + m * 32 + (r & 3) + 8 * (r >> 2);
                // monotone float->u32 key; (key<<32)|idx => min value, then min index
                unsigned kb = __float_as_uint(bv);
                kb = (bv < 0.0f) ? ~kb : (kb | 0x80000000u);
                atomicMin(&rowkey[row], ((unsigned long long)kb << 32) | (unsigned)bi);
            }
        }
    }
}

// ---------------------------------------------------------------------------
// Gather: read winning code from rowkey, emit z_q_x, z_q_x_bar, idxf.
__global__ void vq_gather_kernel(const float* __restrict__ E,
                                 const unsigned long long* __restrict__ rowkey,
                                 float* __restrict__ zq, float* __restrict__ zqb,
                                 float* __restrict__ idxf) {
    const int row = blockIdx.x * 4 + (threadIdx.x >> 6);
    const int lane = threadIdx.x & 63;
    const unsigned k = (unsigned)(rowkey[row] & 0xFFFFFFFFull);
    const float4 v = reinterpret_cast<const float4*>(E + (size_t)k * kD)[lane];
    reinterpret_cast<float4*>(zq + (size_t)row * kD)[lane] = v;
    reinterpret_cast<float4*>(zqb + (size_t)row * kD)[lane] = v;
    if (lane == 0) idxf[row] = (float)k;
}

// ---------------------------------------------------------------------------
extern "C" void kernel_launch(void* const* d_in, const int* in_sizes, int n_in,
                              void* d_out, int out_size, void* d_ws, size_t ws_size,
                              hipStream_t stream) {
    const float* X = (const float*)d_in[0];      // z_e_x  [N, D]
    const float* E = (const float*)d_in[1];      // embedding [K, D]

    float* out  = (float*)d_out;
    float* zq   = out;                           // [N*D]
    float* zqb  = out + (size_t)kN * kD;         // [N*D]
    float* idxf = out + 2 * (size_t)kN * kD;     // [N]

    // X images live in d_out [0,48MB); fully consumed by gemm before gather
    // overwrites (stream order).
    char* ob = (char*)d_out;
    unsigned short* XIh = (unsigned short*)ob;                   // 16 MB
    unsigned short* XIm = XIh + (size_t)kN * kD;                 // 16 MB
    unsigned short* XIl = XIm + (size_t)kN * kD;                 // 16 MB

    // ws: rowkey (256KB) | csqr (4KB) | E images (1.5MB)
    char* ws = (char*)d_ws;
    unsigned long long* rowkey = (unsigned long long*)ws;
    float* csqr = (float*)(ws + (size_t)kN * 8);
    unsigned short* EIh = (unsigned short*)(ws + (size_t)kN * 8 + 4096);
    unsigned short* EIm = EIh + (size_t)kK * kD;
    unsigned short* EIl = EIm + (size_t)kK * kD;

    hipMemsetAsync(rowkey, 0xFF, (size_t)kN * 8, stream);   // +inf keys
    vq_split_all_kernel<<<kN / 64 + kK / 64, 256, 0, stream>>>(
        X, E, XIh, XIm, XIl, EIh, EIm, EIl, csqr);
    vq_gemm_kernel<<<(kN / 256) * (kK / 128), 256, 0, stream>>>(
        XIh, XIm, XIl, EIh, EIm, EIl, csqr, rowkey);
    vq_gather_kernel<<<kN / 4, 256, 0, stream>>>(E, rowkey, zq, zqb, idxf);
}

// Round 7
// 248.788 us; speedup vs baseline: 1.0272x; 1.0077x over previous
//
#include <hip/hip_runtime.h>
#include <float.h>

// Problem constants (B=16, T=2048, D=256, K=1024)
constexpr int kD = 256;
constexpr int kK = 1024;
constexpr int kN = 16 * 2048;   // 32768 rows

using bf16x8 = __attribute__((ext_vector_type(8))) short;
using f32x16 = __attribute__((ext_vector_type(16))) float;
using u16x8  = __attribute__((ext_vector_type(8))) unsigned short;

__device__ __forceinline__ unsigned short f2bf(float x) {
    union { float f; unsigned u; } a; a.f = x;
    const unsigned u = a.u;
    return (unsigned short)((u + 0x7fffu + ((u >> 16) & 1u)) >> 16);   // RNE
}
__device__ __forceinline__ float bf2f(unsigned short b) {
    union { unsigned u; float f; } a; a.u = ((unsigned)b) << 16;
    return a.f;
}

#define GLOAD_LDS16(GP, LP) \
    __builtin_amdgcn_global_load_lds((const __attribute__((address_space(1))) unsigned int*)(GP), \
                                     (__attribute__((address_space(3))) unsigned int*)(LP), 16, 0, 0)

// ---------------------------------------------------------------------------
// Fused split: blocks [0,512) split X, blocks [512,528) split E (+csqr).
// Image layout (validated R3/R5/R6): for 64-row block RB, unit u in [0,2048):
//   l=u&63, f=(u>>6)&1, t16=u>>7
//   row = RB*64 + f*32 + (l&31); d0 = t16*16 + (l>>5)*8
//   shorts offset = RB*16384 + t16*1024 + f*512 + l*8   (d-chunk stride 1024)
__global__ void vq_split_all_kernel(const float* __restrict__ X, const float* __restrict__ E,
                                    unsigned short* __restrict__ xh, unsigned short* __restrict__ xm,
                                    unsigned short* __restrict__ xl,
                                    unsigned short* __restrict__ eh, unsigned short* __restrict__ em,
                                    unsigned short* __restrict__ el,
                                    float* __restrict__ csqr) {
    __shared__ float part[64][4];
    const int b   = blockIdx.x;
    const bool isE = b >= 512;
    const int RB  = isE ? b - 512 : b;
    const float* src = isE ? E : X;
    unsigned short* oh = isE ? eh : xh;
    unsigned short* om = isE ? em : xm;
    unsigned short* ol = isE ? el : xl;
    const int t = threadIdx.x;
    #pragma unroll
    for (int it = 0; it < 8; ++it) {
        const int u   = it * 256 + t;
        const int l   = u & 63;
        const int f   = (u >> 6) & 1;
        const int t16 = u >> 7;
        const int row = RB * 64 + f * 32 + (l & 31);
        const int d0  = t16 * 16 + (l >> 5) * 8;
        const float4 v0 = *reinterpret_cast<const float4*>(src + (size_t)row * kD + d0);
        const float4 v1 = *reinterpret_cast<const float4*>(src + (size_t)row * kD + d0 + 4);
        const float x[8] = {v0.x, v0.y, v0.z, v0.w, v1.x, v1.y, v1.z, v1.w};
        u16x8 H, M, L;
        #pragma unroll
        for (int e = 0; e < 8; ++e) {
            const unsigned short h = f2bf(x[e]);
            const float r1 = x[e] - bf2f(h);          // exact
            const unsigned short m = f2bf(r1);
            const float r2 = r1 - bf2f(m);            // exact
            const unsigned short lo = f2bf(r2);
            H[e] = (short)h; M[e] = (short)m; L[e] = (short)lo;
        }
        const size_t o = (size_t)RB * 16384 + (size_t)u * 8;
        *reinterpret_cast<u16x8*>(oh + o) = H;
        *reinterpret_cast<u16x8*>(om + o) = M;
        *reinterpret_cast<u16x8*>(ol + o) = L;
    }
    if (isE) {
        const int r = t >> 2, q = t & 3;
        const float* rp = E + (size_t)(RB * 64 + r) * kD + q * 64;
        float s = 0.0f;
        #pragma unroll
        for (int i = 0; i < 16; ++i) {
            const float4 v = reinterpret_cast<const float4*>(rp)[i];
            s += v.x * v.x + v.y * v.y + v.z * v.z + v.w * v.w;
        }
        part[r][q] = s;
        __syncthreads();
        if (t < 64) csqr[RB * 64 + t] = part[t][0] + part[t][1] + part[t][2] + part[t][3];
    }
}

// ---------------------------------------------------------------------------
// MFMA distance GEMM, 8-phase-style schedule (6 phases = the 6 bf16x3 passes).
// 512 thr / 8 waves (2M x 4N); tile 256x256; wave tile 128x64 (acc[4][2]).
// Per phase: {ds_read frags first needed ∥ 2 staging loads} -> s_barrier ->
// lgkmcnt(0) -> setprio(1) -> 8 MFMA -> setprio(0) -> s_barrier.
// vmcnt(0) once per chunk, 3+ phases after its loads were issued (free).
// dist(r,c) = csqr[c] - 2*dot  (||x||^2 dropped: argmin-invariant per row).
__global__ __launch_bounds__(512, 2) void vq_gemm_kernel(
    const unsigned short* __restrict__ xh, const unsigned short* __restrict__ xm,
    const unsigned short* __restrict__ xl,
    const unsigned short* __restrict__ eh, const unsigned short* __restrict__ em,
    const unsigned short* __restrict__ el,
    const float* __restrict__ csqr,
    unsigned long long* __restrict__ rowkey)
{
    // per buffer: A = 24 segs (4 grp x 2 f x 3 lv), B = 24 segs, 1 KB each
    __shared__ bf16x8 smem[2][3072];      // 96 KB
    const int tid  = threadIdx.x;
    const int lane = tid & 63;
    const int wid  = tid >> 6;            // 0..7
    const int wr   = wid >> 2;            // 0..1: rows wr*128
    const int wc   = wid & 3;             // 0..3: cols wc*64

    // XCD-bijective: the 4 col-blocks of each 256-row panel land on one XCD.
    const int w    = blockIdx.x;          // 512 blocks
    const int xcd  = w & 7;
    const int slot = w >> 3;              // 0..63
    const int rbp  = xcd * 16 + (slot >> 2);   // 0..127 row panel (256 rows)
    const int cbp  = slot & 3;                 // 0..3  col block (256 codes)

    // 6 staging descriptors per wave (48 segs / 8 waves).
    const unsigned short* gbase[6];
    int ldsoff[6];
    #pragma unroll
    for (int k2 = 0; k2 < 6; ++k2) {
        const int s = wid * 6 + k2;            // 0..47
        const bool isB = s >= 24;
        const int q   = isB ? s - 24 : s;      // 0..23
        const int grp = q / 6;                 // 0..3
        const int rem = q % 6;
        const int f   = rem / 3;
        const int lv  = rem % 3;
        const unsigned short* img = isB ? (lv == 0 ? eh : lv == 1 ? em : el)
                                        : (lv == 0 ? xh : lv == 1 ? xm : xl);
        const int RBx = isB ? (cbp * 4 + grp) : (rbp * 4 + grp);
        gbase[k2] = img + (size_t)RBx * 16384 + f * 512 + lane * 8;
        ldsoff[k2] = (isB ? 1536 : 0) + q * 64;
    }

    f32x16 acc[4][2];
    #pragma unroll
    for (int m = 0; m < 4; ++m) { acc[m][0] = (f32x16)0.0f; acc[m][1] = (f32x16)0.0f; }

    // Frag bases (element index into a smem buffer); +lv*64 per level.
    int au[4], bu[2];
    #pragma unroll
    for (int m = 0; m < 4; ++m) au[m] = ((wr * 2 + (m >> 1)) * 6 + (m & 1) * 3) * 64 + lane;
    #pragma unroll
    for (int n = 0; n < 2; ++n) bu[n] = 1536 + (wc * 6 + n * 3) * 64 + lane;

#define BARRIER() do { asm volatile("" ::: "memory"); __builtin_amdgcn_s_barrier(); \
                       asm volatile("" ::: "memory"); } while (0)
#define LGK0() asm volatile("s_waitcnt lgkmcnt(0)" ::: "memory")
#define MMPASS(AX, BX) do { \
    __builtin_amdgcn_s_setprio(1); \
    _Pragma("unroll") \
    for (int n_ = 0; n_ < 2; ++n_) { \
        _Pragma("unroll") \
        for (int m_ = 0; m_ < 4; ++m_) \
            acc[m_][n_] = __builtin_amdgcn_mfma_f32_32x32x16_bf16(AX[m_], BX[n_], acc[m_][n_], 0, 0, 0); \
    } \
    __builtin_amdgcn_s_setprio(0); \
} while (0)
#define STAGE2(P) do { if (st) { \
    GLOAD_LDS16(gbase[2 * (P)] + co, &nb[ldsoff[2 * (P)]]); \
    GLOAD_LDS16(gbase[2 * (P) + 1] + co, &nb[ldsoff[2 * (P) + 1]]); } } while (0)

    // Prologue: stage chunk 0 fully (6 segs/wave), drain, barrier.
    #pragma unroll
    for (int k2 = 0; k2 < 6; ++k2) GLOAD_LDS16(gbase[k2], &smem[0][ldsoff[k2]]);
    asm volatile("s_waitcnt vmcnt(0)" ::: "memory");
    BARRIER();

    #pragma unroll 1
    for (int c = 0; c < 16; ++c) {
        const bf16x8* sb = smem[c & 1];
        bf16x8* nb = smem[(c + 1) & 1];
        const bool st = (c < 15);
        const size_t co = (size_t)(c + 1) * 1024;
        bf16x8 A0[4], A1[4], A2[4], B0[2], B1[2], B2[2];

        // P0: read Ah, Bh; stage segs 0,1  -> hh
        #pragma unroll
        for (int m = 0; m < 4; ++m) A0[m] = sb[au[m]];
        #pragma unroll
        for (int n = 0; n < 2; ++n) B0[n] = sb[bu[n]];
        STAGE2(0);
        BARRIER(); LGK0();
        MMPASS(A0, B0);
        BARRIER();

        // P1: read Bm; stage segs 2,3  -> hm
        #pragma unroll
        for (int n = 0; n < 2; ++n) B1[n] = sb[bu[n] + 64];
        STAGE2(1);
        BARRIER(); LGK0();
        MMPASS(A0, B1);
        BARRIER();

        // P2: read Am; stage segs 4,5  -> mh
        #pragma unroll
        for (int m = 0; m < 4; ++m) A1[m] = sb[au[m] + 64];
        STAGE2(2);
        BARRIER(); LGK0();
        MMPASS(A1, B0);
        BARRIER();

        // P3: read Bl  -> hl
        #pragma unroll
        for (int n = 0; n < 2; ++n) B2[n] = sb[bu[n] + 128];
        BARRIER(); LGK0();
        MMPASS(A0, B2);
        BARRIER();

        // P4: read Al  -> lh
        #pragma unroll
        for (int m = 0; m < 4; ++m) A2[m] = sb[au[m] + 128];
        BARRIER(); LGK0();
        MMPASS(A2, B0);
        BARRIER();

        // P5: mm; then own staging segs (issued P0-P2, ~3 phases ago) must be
        // landed before any wave reads the new buffer -> vmcnt(0) + barrier.
        MMPASS(A1, B1);
        asm volatile("s_waitcnt vmcnt(0)" ::: "memory");
        BARRIER();
    }
#undef STAGE2
#undef MMPASS
#undef LGK0
#undef BARRIER

    // Epilogue. C/D layout: col = lane&31, row = (reg&3)+8*(reg>>2)+4*(lane>>5).
    const int lane31 = lane & 31;
    const int colbase = cbp * 256 + wc * 64;
    const float cs0 = csqr[colbase + lane31];
    const float cs1 = csqr[colbase + 32 + lane31];
    const int rowbase = rbp * 256 + wr * 128 + 4 * (lane >> 5);

    #pragma unroll
    for (int m = 0; m < 4; ++m) {
        #pragma unroll
        for (int r = 0; r < 16; ++r) {
            float bv = fmaf(-2.0f, acc[m][0][r], cs0);
            int   bi = colbase + lane31;
            const float v1 = fmaf(-2.0f, acc[m][1][r], cs1);
            if (v1 < bv) { bv = v1; bi = colbase + 32 + lane31; }
            #pragma unroll
            for (int mk = 16; mk >= 1; mk >>= 1) {      // reduce within 32-lane half
                const float ov = __shfl_xor(bv, mk);
                const int   oi = __shfl_xor(bi, mk);
                if (ov < bv || (ov == bv && oi < bi)) { bv = ov; bi = oi; }
            }
            if (lane31 == 0) {
                const int row = rowbase + m * 32 + (r & 3) + 8 * (r >> 2);
                // monotone float->u32 key; (key<<32)|idx => min value, then min index
                unsigned kb = __float_as_uint(bv);
                kb = (bv < 0.0f) ? ~kb : (kb | 0x80000000u);
                atomicMin(&rowkey[row], ((unsigned long long)kb << 32) | (unsigned)bi);
            }
        }
    }
}

// ---------------------------------------------------------------------------
// Gather: read winning code from rowkey, emit z_q_x, z_q_x_bar, idxf.
__global__ void vq_gather_kernel(const float* __restrict__ E,
                                 const unsigned long long* __restrict__ rowkey,
                                 float* __restrict__ zq, float* __restrict__ zqb,
                                 float* __restrict__ idxf) {
    const int row = blockIdx.x * 4 + (threadIdx.x >> 6);
    const int lane = threadIdx.x & 63;
    const unsigned k = (unsigned)(rowkey[row] & 0xFFFFFFFFull);
    const float4 v = reinterpret_cast<const float4*>(E + (size_t)k * kD)[lane];
    reinterpret_cast<float4*>(zq + (size_t)row * kD)[lane] = v;
    reinterpret_cast<float4*>(zqb + (size_t)row * kD)[lane] = v;
    if (lane == 0) idxf[row] = (float)k;
}

// ---------------------------------------------------------------------------
extern "C" void kernel_launch(void* const* d_in, const int* in_sizes, int n_in,
                              void* d_out, int out_size, void* d_ws, size_t ws_size,
                              hipStream_t stream) {
    const float* X = (const float*)d_in[0];      // z_e_x  [N, D]
    const float* E = (const float*)d_in[1];      // embedding [K, D]

    float* out  = (float*)d_out;
    float* zq   = out;                           // [N*D]
    float* zqb  = out + (size_t)kN * kD;         // [N*D]
    float* idxf = out + 2 * (size_t)kN * kD;     // [N]

    // X images live in d_out [0,48MB); fully consumed by gemm before gather
    // overwrites (stream order).
    char* ob = (char*)d_out;
    unsigned short* XIh = (unsigned short*)ob;                   // 16 MB
    unsigned short* XIm = XIh + (size_t)kN * kD;                 // 16 MB
    unsigned short* XIl = XIm + (size_t)kN * kD;                 // 16 MB

    // ws: rowkey (256KB) | csqr (4KB) | E images (1.5MB)
    char* ws = (char*)d_ws;
    unsigned long long* rowkey = (unsigned long long*)ws;
    float* csqr = (float*)(ws + (size_t)kN * 8);
    unsigned short* EIh = (unsigned short*)(ws + (size_t)kN * 8 + 4096);
    unsigned short* EIm = EIh + (size_t)kK * kD;
    unsigned short* EIl = EIm + (size_t)kK * kD;

    hipMemsetAsync(rowkey, 0xFF, (size_t)kN * 8, stream);   // +inf keys
    vq_split_all_kernel<<<kN / 64 + kK / 64, 256, 0, stream>>>(
        X, E, XIh, XIm, XIl, EIh, EIm, EIl, csqr);
    vq_gemm_kernel<<<(kN / 256) * (kK / 256), 512, 0, stream>>>(
        XIh, XIm, XIl, EIh, EIm, EIl, csqr, rowkey);
    vq_gather_kernel<<<kN / 4, 256, 0, stream>>>(E, rowkey, zq, zqb, idxf);
}